// Round 13
// baseline (230.380 us; speedup 1.0000x reference)
//
#include <hip/hip_runtime.h>
#include <hip/hip_bf16.h>
#include <math.h>

typedef unsigned short ushort_t;
typedef unsigned int   u32;
typedef __attribute__((ext_vector_type(8))) short s8v;
typedef __attribute__((ext_vector_type(4))) float f4v;

#define LL 64
#define NB 64
#define NSITE 4096
#define BN 262144
#define WA_OFF 1408
#define WB_OFF 1536
#define PL_OFF 4096
#define BF_OFF (PL_OFF + 6*BN)   // float index; region holds 2048 s8v (bf16-rne W2 fragments)
// ws float layout:
//  [0,640)     red[b*10 + {S1,S2,Sd1_c0..3,Sd2_c0..3}]   (atomically accumulated)
//  [640,704)   lapl[b]                                   (atomically accumulated)
//  [704,768)   per-batch completion counters (int)       (zeroed by k_pre)
//  [1408,1536) wa, [1536,1664) wb
//  [4096, +6*BN) planes: h, RA, RB, TAa, TAb, TBb
//  [BF_OFF, +8192) pre-rounded W2 fragments (bf16)

// fast exact-GELU: value + 1st/2nd derivative. erf via A&S 7.1.26 (|eps|<=1.5e-7)
__device__ __forceinline__ void gelu3(float u, float &h, float &d, float &e){
  float E   = __expf(-0.5f * u * u);
  float phi = 0.3989422804014327f * E;
  float az  = fabsf(u) * 0.70710678118654752f;
  float t   = __builtin_amdgcn_rcpf(1.0f + 0.3275911f * az);
  float p   = t*(0.254829592f + t*(-0.284496736f + t*(1.421413741f + t*(-1.453152027f + t*1.061405429f))));
  float erfabs = 1.0f - p * E;
  float erfv   = __builtin_copysignf(erfabs, u);
  float Phi = 0.5f * (1.0f + erfv);
  h = u * Phi;
  d = Phi + u * phi;
  e = phi * (2.0f - u * u);
}

// 16-lane row reduction entirely in the VALU pipe (DPP), no LDS ops.
#define DPP_ADD(v, ctrl) { \
  int _si = __builtin_amdgcn_update_dpp(0, __builtin_bit_cast(int, v), ctrl, 0xf, 0xf, true); \
  v += __builtin_bit_cast(float, _si); }

__device__ __forceinline__ float redjb16(float v){
  DPP_ADD(v, 0xB1);
  DPP_ADD(v, 0x4E);
  DPP_ADD(v, 0x124);
  DPP_ADD(v, 0x128);
  return v;
}
// 64-lane reduction: 4 DPP stages within rows + 2 cross-row shuffles
__device__ __forceinline__ float red64(float v){
  v = redjb16(v);
  v += __shfl_xor(v, 16);
  v += __shfl_xor(v, 32);
  return v;
}

__device__ __forceinline__ ushort_t bf16rne(float v){
  union { float f; u32 i; } x; x.f = v;
  u32 r = x.i + 0x7FFFu + ((x.i >> 16) & 1u);
  return (ushort_t)(r >> 16);
}
// packed rne bf16 of two floats -> u32 (low = a, high = b); lowers to v_cvt_pk_bf16_f32
__device__ __forceinline__ u32 pkbf(float a, float b){
  __hip_bfloat162 t = __float22bfloat162_rn(make_float2(a, b));
  u32 r;
  __builtin_memcpy(&r, &t, sizeof(r));
  return r;
}

// ---------------- one-time prep: zero accumulators + wa/wb + W2 rne-bf16 fragments ----------------
__global__ __launch_bounds__(256, 4) void k_pre(
    const float* __restrict__ W1g, const float* __restrict__ W2g,
    float* __restrict__ ws)
{
  int t = blockIdx.x * 256 + threadIdx.x;     // 0..2047
  if (t < 768) ws[t] = 0.0f;                  // red + lapl + counters
  if (blockIdx.x == 0 && threadIdx.x < 128) {
    int k = threadIdx.x;
    ws[WA_OFF + k] = W1g[k] + W1g[256+k] + W1g[384+k];
    ws[WB_OFF + k] = W1g[128+k];
  }
  short* BF = (short*)(ws + BF_OFF);
  int w = t >> 9, nt = (t >> 8) & 1, kt = (t >> 6) & 3, lane = t & 63;
  int q = lane >> 4, nlo = lane & 15;
  int n = w*32 + nt*16 + nlo;
  s8v vh;
  #pragma unroll
  for (int jj = 0; jj < 8; ++jj) {
    int k = kt*32 + q*8 + jj;
    vh[jj] = (short)bf16rne(W2g[k*128 + n]);
  }
  *(s8v*)&BF[t*8] = vh;
}

// ---------------- heavy kernel: one (batch, 4-row group), 16 chunks of 16 sites ----------------
// grid 1024 = 64 b * 16 row-groups ; block 256 (4 waves); 4 blocks/CU
// pure bf16-rne MFMA path: 48 MFMA + 6 subplanes per chunk.
__global__ __launch_bounds__(256, 4) void k_c1(
    const float* __restrict__ xg, const int* __restrict__ signs,
    const float* __restrict__ b1g, const float* __restrict__ b2g,
    const float* __restrict__ W3g, const float* __restrict__ b3g,
    float* __restrict__ ws)
{
  // AF: [kt(4)][plane(6)] x 512 shorts ; planes: {h, d*wa, d*wb, e*waa, e*wab, e*wbb}
  __shared__ short AF[12288];                 // 24 KB
  __shared__ float xS[6][64];                 // rows i0-1..i0+4  (1.5 KB)
  __shared__ char  zS[6][64];                 // signs as +-1     (384 B)
  __shared__ float EP[16][6][4];              // 1.5 KB

  const int tid  = threadIdx.x;
  const int lane = tid & 63;
  const int w    = tid >> 6;
  const int q    = lane >> 4;
  const int nlo  = lane & 15;

  const int blk = blockIdx.x;
  const int b   = blk >> 4;
  const int i0  = (blk & 15) << 2;            // first of four rows

  // per-thread B-fragment pointer (L2-resident pre-rounded W2)
  const s8v* BhT = (const s8v*)((const short*)(ws + BF_OFF)) + (w*512 + lane);

  float b2j[2], w3j[2];
  #pragma unroll
  for (int nt = 0; nt < 2; ++nt) {
    int j = w*32 + nt*16 + nlo;
    b2j[nt] = b2g[j];
    w3j[nt] = W3g[j];
  }
  float b3v = b3g[0];

  // ---- stage 6 x-rows and 6 sign-rows ----
  for (int t = tid; t < 384; t += 256) {
    int r = t >> 6, j = t & 63;
    int gr = (i0 - 1 + r) & 63;
    xS[r][j] = xg[(size_t)b*NSITE + gr*64 + j];
    int c = ((gr & 1) << 1) | (j & 1);
    zS[r][j] = (char)(2*signs[((c*NB + b)*LL + gr)*LL + j] - 1);
  }
  __syncthreads();

  float racc[10];
  #pragma unroll
  for (int n = 0; n < 10; ++n) racc[n] = 0.f;

  #pragma unroll 1
  for (int ch = 0; ch < 16; ++ch) {
    const int lr = 1 + (ch >> 2);             // local row 1..4
    const int jb = ch & 3;
    const int i  = i0 + (ch >> 2);

    // ---- P1: build A fragments (jj pairs, packed bf16 converts) ----
    {
      int s  = tid & 15;
      int ko = tid >> 4;
      int kt = ko >> 2, kg = ko & 3;
      int j = jb*16 + s, jm = (j+63)&63, jp = (j+1)&63;
      float p = xS[lr][j];
      float l = xS[lr-1][j] + xS[lr+1][j] + xS[lr][jm] + xS[lr][jp] - 4.0f*p;
      short* base = &AF[kt*3072 + (kg*16 + s)*8];
      #pragma unroll
      for (int half = 0; half < 2; ++half) {
        int k0 = ko*8 + half*4;
        float4 wa4 = *(const float4*)(ws + WA_OFF + k0);
        float4 wb4 = *(const float4*)(ws + WB_OFF + k0);
        float4 b14 = *(const float4*)(b1g + k0);
        const float* waA = (const float*)&wa4;
        const float* wbA = (const float*)&wb4;
        const float* b1A = (const float*)&b14;
        u32 v[12];                            // 6 planes x 2 u32 (4 bf16)
        #pragma unroll
        for (int pr = 0; pr < 2; ++pr) {
          float wa0 = waA[pr*2], wa1 = waA[pr*2+1];
          float wb0 = wbA[pr*2], wb1 = wbA[pr*2+1];
          float u0 = p*wa0 + l*wb0 + b1A[pr*2];
          float u1 = p*wa1 + l*wb1 + b1A[pr*2+1];
          float h0, d0, e0, h1, d1, e1;
          gelu3(u0, h0, d0, e0);
          gelu3(u1, h1, d1, e1);
          v[0*2+pr] = pkbf(h0, h1);
          v[1*2+pr] = pkbf(d0*wa0, d1*wa1);
          v[2*2+pr] = pkbf(d0*wb0, d1*wb1);
          float ea0 = e0*wa0, ea1 = e1*wa1;
          float eb0 = e0*wb0, eb1 = e1*wb1;
          v[3*2+pr] = pkbf(ea0*wa0, ea1*wa1);
          v[4*2+pr] = pkbf(ea0*wb0, ea1*wb1);
          v[5*2+pr] = pkbf(eb0*wb0, eb1*wb1);
        }
        short* hb = base + half*4;
        #pragma unroll
        for (int pp = 0; pp < 6; ++pp)
          *(int2*)&hb[pp*512] = make_int2((int)v[pp*2], (int)v[pp*2+1]);
      }
    }
    __syncthreads();

    // ---- P2: MFMA, 6 planes x 2 nt per kt, B prefetched 1-ahead ----
    f4v acc[6][2];
    #pragma unroll
    for (int pp = 0; pp < 6; ++pp)
      #pragma unroll
      for (int nt = 0; nt < 2; ++nt)
        acc[pp][nt] = (f4v){0.f, 0.f, 0.f, 0.f};

    s8v bh0 = BhT[0], bh1 = BhT[256];
    #pragma unroll 1
    for (int kt = 0; kt < 4; ++kt) {
      s8v nh0 = bh0, nh1 = bh1;
      if (kt != 3) {
        int o = (kt + 1) * 64;
        nh0 = BhT[o]; nh1 = BhT[256 + o];
      }
      const short* base = &AF[kt*3072 + lane*8];
      #pragma unroll
      for (int pp = 0; pp < 6; ++pp) {
        s8v ah = *(const s8v*)&base[pp*512];
        acc[pp][0] = __builtin_amdgcn_mfma_f32_16x16x32_bf16(ah, bh0, acc[pp][0], 0, 0, 0);
        acc[pp][1] = __builtin_amdgcn_mfma_f32_16x16x32_bf16(ah, bh1, acc[pp][1], 0, 0, 0);
      }
      bh0 = nh0; bh1 = nh1;
    }

    // ---- P3: epilogue (r-outer; DPP reductions — zero LDS ops) ----
    {
      #pragma unroll
      for (int r = 0; r < 4; ++r) {
        float sh=0.f, sA=0.f, sB=0.f, sa=0.f, sb=0.f, sc=0.f;
        #pragma unroll
        for (int nt = 0; nt < 2; ++nt) {
          float uu = acc[0][nt][r] + b2j[nt];
          float h2, d2, e2;
          gelu3(uu, h2, d2, e2);
          float wd = w3j[nt] * d2, we = w3j[nt] * e2;
          float A  = acc[1][nt][r], Bv = acc[2][nt][r];
          sh += w3j[nt] * h2;
          sA += wd * A;
          sB += wd * Bv;
          sa += we * A * A   + wd * acc[3][nt][r];
          sb += we * A * Bv  + wd * acc[4][nt][r];
          sc += we * Bv * Bv + wd * acc[5][nt][r];
        }
        sh = redjb16(sh); sA = redjb16(sA); sB = redjb16(sB);
        sa = redjb16(sa); sb = redjb16(sb); sc = redjb16(sc);
        if (nlo == 0) {
          int site = q*4 + r;
          EP[site][0][w] = sh;
          EP[site][1][w] = sA;
          EP[site][2][w] = sB;
          EP[site][3][w] = sa;
          EP[site][4][w] = sb;
          EP[site][5][w] = sc;
        }
      }
    }
    __syncthreads();

    // ---- P4: per-site finalize + batch accumulation (16 threads) ----
    if (tid < 16) {
      int s = tid;
      float h = 0.f, RA = 0.f, RB = 0.f, TAa = 0.f, TAb = 0.f, TBb = 0.f;
      #pragma unroll
      for (int ww = 0; ww < 4; ++ww) {
        h   += EP[s][0][ww];
        RA  += EP[s][1][ww];
        RB  += EP[s][2][ww];
        TAa += EP[s][3][ww];
        TAb += EP[s][4][ww];
        TBb += EP[s][5][ww];
      }
      h += b3v;
      float* P = ws + PL_OFF;
      int j = jb*16 + s;
      size_t site = (size_t)b*NSITE + i*64 + j;
      P[0*BN + site] = h;
      P[1*BN + site] = RA;
      P[2*BN + site] = RB;
      P[3*BN + site] = TAa;
      P[4*BN + site] = TAb;
      P[5*BN + site] = TBb;

      int jm = (j+63)&63, jp = (j+1)&63;
      int c0 = ((i & 1) << 1) | (j & 1);
      float hd[4] = {0.f, 0.f, 0.f, 0.f};
      hd[c0]     = (float)zS[lr][j] * (RA - 4.0f*RB);
      hd[c0 ^ 1] = (float)(zS[lr][jm] + zS[lr][jp]) * RB;
      hd[c0 ^ 2] = (float)(zS[lr-1][j] + zS[lr+1][j]) * RB;
      racc[0] += h;
      racc[1] += h*h;
      #pragma unroll
      for (int cc = 0; cc < 4; ++cc) {
        racc[2+cc] += hd[cc];
        racc[6+cc] += h*hd[cc];
      }
    }
  }

  // ---- final batch reduction: one atomic set per block ----
  if (tid < 16) {
    #pragma unroll
    for (int n = 0; n < 10; ++n) racc[n] = redjb16(racc[n]);
    if (tid == 0) {
      #pragma unroll
      for (int n = 0; n < 10; ++n) atomicAdd(&ws[b*10 + n], racc[n]);
    }
  }
}

// ---------------- stencil + fused head calculus + last-block lapl write ----------------
__global__ __launch_bounds__(256, 1) void k_c2(
    const int* __restrict__ signs,
    const float* __restrict__ aW1g, const float* __restrict__ ab1g,
    const float* __restrict__ aW2g,
    float* __restrict__ ws, float* __restrict__ out)
{
  __shared__ float part[4];
  __shared__ float coefL[10];
  __shared__ float cbS[6][64];
  int blk = blockIdx.x;
  int b = blk >> 4, rg = blk & 15;
  int tid = threadIdx.x;

  if (tid < 64) {
    int k = tid;
    const float Nf = 4096.0f, Nm1 = 4095.0f;
    float S1 = ws[b*10+0], S2 = ws[b*10+1];
    float m = S1/Nf, q = S2/Nf;
    float v = (S2 - S1*S1/Nf)/Nm1;
    float w0 = aW1g[k], w1 = aW1g[64+k], w2 = aW1g[128+k];
    float t = m*w0 + v*w1 + q*w2 + ab1g[k];
    float gh, gd, ge;
    gelu3(t, gh, gd, ge);
    float o = aW2g[k];
    float g1o = gd*o, g2o = ge*o;
    float da0 = w0*g1o, da1 = w1*g1o, da2 = w2*g1o;
    float M00 = w0*w0*g2o, M01 = w0*w1*g2o, M02 = w0*w2*g2o;
    float M11 = w1*w1*g2o, M12 = w1*w2*g2o, M22 = w2*w2*g2o;
    da0 = red64(da0); da1 = red64(da1); da2 = red64(da2);
    M00 = red64(M00); M01 = red64(M01); M02 = red64(M02);
    M11 = red64(M11); M12 = red64(M12); M22 = red64(M22);
    if (k == 0) {
      coefL[0] = da0/Nf - 2.0f*da1*m/Nm1;
      coefL[1] = 2.0f*da1/Nm1 + 2.0f*da2/Nf;
      #pragma unroll
      for (int c = 0; c < 4; ++c) {
        float s1 = ws[b*10 + 2 + c], s2 = ws[b*10 + 6 + c];
        float md = s1/Nf, qd = 2.0f*s2/Nf;
        float vd = (2.0f*s2 - 2.0f*S1*s1/Nf)/Nm1;
        float dd0 = M00*md + M01*vd + M02*qd;
        float dd1 = M01*md + M11*vd + M12*qd;
        float dd2 = M02*md + M12*vd + M22*qd;
        coefL[2+c] = dd0/Nf - 2.0f*(dd1*m + da1*md)/Nm1;
        coefL[6+c] = 2.0f*dd1/Nm1 + 2.0f*dd2/Nf;
      }
    }
  }
  __syncthreads();

  const float* P = ws + PL_OFF;
  int base = b*NSITE;
  float alpha = coefL[0], beta = coefL[1];

  // stage cb = (alpha + beta*h) * RB for rows rg*4-1 .. rg*4+4
  for (int t = tid; t < 384; t += 256) {
    int r = t >> 6, jj = t & 63;
    int gr = (rg*4 - 1 + r) & 63;
    int sidx = base + gr*64 + jj;
    cbS[r][jj] = (alpha + beta*P[sidx]) * P[2*BN + sidx];
  }
  __syncthreads();

  int rl = tid >> 6, j = tid & 63;
  int i = rg*4 + rl;
  int im=(i+63)&63, ip=(i+1)&63, jm=(j+63)&63, jp=(j+1)&63;
  int s  = base + i*64 + j;
  float h  = P[s], RA = P[BN+s], RB = P[2*BN+s];
  float TAa= P[3*BN+s], TAb = P[4*BN+s], TBb = P[5*BN+s];
  float g  = alpha + beta*h;
  int lr2 = rl + 1;
  float cb  = cbS[lr2][j];
  float cbu = cbS[lr2-1][j], cbd = cbS[lr2+1][j];
  float cbl = cbS[lr2][jm],  cbr = cbS[lr2][jp];
  float grad = g*RA + (cbu + cbd + cbl + cbr - 4.0f*cb);
  out[(size_t)b*4097 + i*64 + j] = grad;

  int c0 = ((i & 1) << 1) | (j & 1);
  int c1 = c0 ^ 1, c2 = c0 ^ 2;
  float zv = 2.0f*(float)signs[((c0*NB + b)*LL + i )*LL + j ] - 1.0f;
  float zl = 2.0f*(float)signs[((c1*NB + b)*LL + i )*LL + jm] - 1.0f;
  float zr = 2.0f*(float)signs[((c1*NB + b)*LL + i )*LL + jp] - 1.0f;
  float zu = 2.0f*(float)signs[((c2*NB + b)*LL + im)*LL + j ] - 1.0f;
  float zd = 2.0f*(float)signs[((c2*NB + b)*LL + ip)*LL + j ] - 1.0f;
  float sjr = zl + zr, sud = zu + zd;
  float hd0 = zv*(RA - 4.0f*RB);
  float hd1 = sjr*RB, hd2 = sud*RB;
  float gd0 = coefL[2+c0] + coefL[6+c0]*h + beta*hd0;
  float gd1 = coefL[2+c1] + coefL[6+c1]*h + beta*hd1;
  float gd2 = coefL[2+c2] + coefL[6+c2]*h + beta*hd2;
  float ca0 = gd0*RA + g*( zv*TAa - 4.0f*zv*TAb );
  float cb0 = gd0*RB + g*( zv*TAb - 4.0f*zv*TBb );
  float cb1 = gd1*RB + g*( sjr*TBb );
  float cb2 = gd2*RB + g*( sud*TBb );
  float contrib = zv*ca0 - 4.0f*zv*cb0 + sjr*cb1 + sud*cb2;

  float vsum = red64(contrib);
  int wv = tid >> 6;
  if ((tid & 63) == 0) part[wv] = vsum;
  __syncthreads();
  if (tid == 0) {
    atomicAdd(&ws[640 + b], part[0]+part[1]+part[2]+part[3]);
    __threadfence();
    u32* cnt = (u32*)(ws + 704);
    u32 old = atomicAdd(&cnt[b], 1u);
    if (old == 15u) {
      // all 16 blocks' value-adds complete (each fenced before its counter-add);
      // coherent read via device-scope RMW
      float tot = atomicAdd(&ws[640 + b], 0.0f);
      out[(size_t)b*4097 + 4096] = tot;
    }
  }
}

extern "C" void kernel_launch(void* const* d_in, const int* in_sizes, int n_in,
                              void* d_out, int out_size, void* d_ws, size_t ws_size,
                              hipStream_t stream) {
  const float* xg    = (const float*)d_in[0];
  const int*   signs = (const int*)d_in[1];
  const float* W1    = (const float*)d_in[2];
  const float* b1    = (const float*)d_in[3];
  const float* W2    = (const float*)d_in[4];
  const float* b2    = (const float*)d_in[5];
  const float* W3    = (const float*)d_in[6];
  const float* b3    = (const float*)d_in[7];
  const float* aW1   = (const float*)d_in[8];
  const float* ab1   = (const float*)d_in[9];
  const float* aW2   = (const float*)d_in[10];
  float* ws  = (float*)d_ws;
  float* out = (float*)d_out;

  hipLaunchKernelGGL(k_pre, dim3(8),    dim3(256), 0, stream, W1, W2, ws);
  hipLaunchKernelGGL(k_c1,  dim3(1024), dim3(256), 0, stream,
                     xg, signs, b1, b2, W3, b3, ws);
  hipLaunchKernelGGL(k_c2,  dim3(1024), dim3(256), 0, stream,
                     signs, aW1, ab1, aW2, ws, out);
}

// Round 14
// 203.017 us; speedup vs baseline: 1.1348x; 1.1348x over previous
//
#include <hip/hip_runtime.h>
#include <hip/hip_bf16.h>
#include <math.h>

typedef unsigned short ushort_t;
typedef unsigned int   u32;
typedef __attribute__((ext_vector_type(8))) short s8v;
typedef __attribute__((ext_vector_type(4))) float f4v;

#define LL 64
#define NB 64
#define NSITE 4096
#define BN 262144
#define RED_OFF 0         // [0,10240): per-block red partials, blk*10+n
#define LP_OFF  10240     // [10240,11264): per-block lapl partials (k_c2 blk)
#define WA_OFF  11264
#define WB_OFF  11392
#define PL_OFF  12288     // planes: h, RA, RB, TAa, TAb, TBb (6*BN floats)
#define BF_OFF  (PL_OFF + 6*BN)   // 2048 s8v (bf16-rne W2 fragments)

// fast exact-GELU: value + 1st/2nd derivative. erf via A&S 7.1.26 (|eps|<=1.5e-7)
__device__ __forceinline__ void gelu3(float u, float &h, float &d, float &e){
  float E   = __expf(-0.5f * u * u);
  float phi = 0.3989422804014327f * E;
  float az  = fabsf(u) * 0.70710678118654752f;
  float t   = __builtin_amdgcn_rcpf(1.0f + 0.3275911f * az);
  float p   = t*(0.254829592f + t*(-0.284496736f + t*(1.421413741f + t*(-1.453152027f + t*1.061405429f))));
  float erfabs = 1.0f - p * E;
  float erfv   = __builtin_copysignf(erfabs, u);
  float Phi = 0.5f * (1.0f + erfv);
  h = u * Phi;
  d = Phi + u * phi;
  e = phi * (2.0f - u * u);
}

// 16-lane row reduction entirely in the VALU pipe (DPP), no LDS ops.
#define DPP_ADD(v, ctrl) { \
  int _si = __builtin_amdgcn_update_dpp(0, __builtin_bit_cast(int, v), ctrl, 0xf, 0xf, true); \
  v += __builtin_bit_cast(float, _si); }

__device__ __forceinline__ float redjb16(float v){
  DPP_ADD(v, 0xB1);
  DPP_ADD(v, 0x4E);
  DPP_ADD(v, 0x124);
  DPP_ADD(v, 0x128);
  return v;
}
// 64-lane reduction: 4 DPP stages within rows + 2 cross-row shuffles
__device__ __forceinline__ float red64(float v){
  v = redjb16(v);
  v += __shfl_xor(v, 16);
  v += __shfl_xor(v, 32);
  return v;
}

__device__ __forceinline__ ushort_t bf16rne(float v){
  union { float f; u32 i; } x; x.f = v;
  u32 r = x.i + 0x7FFFu + ((x.i >> 16) & 1u);
  return (ushort_t)(r >> 16);
}
// packed rne bf16 of two floats -> u32 (low = a, high = b); lowers to v_cvt_pk_bf16_f32
__device__ __forceinline__ u32 pkbf(float a, float b){
  __hip_bfloat162 t = __float22bfloat162_rn(make_float2(a, b));
  u32 r;
  __builtin_memcpy(&r, &t, sizeof(r));
  return r;
}

// ---------------- one-time prep: wa/wb + W2 rne-bf16 fragments ----------------
__global__ __launch_bounds__(256, 4) void k_pre(
    const float* __restrict__ W1g, const float* __restrict__ W2g,
    float* __restrict__ ws)
{
  int t = blockIdx.x * 256 + threadIdx.x;     // 0..2047
  if (blockIdx.x == 0 && threadIdx.x < 128) {
    int k = threadIdx.x;
    ws[WA_OFF + k] = W1g[k] + W1g[256+k] + W1g[384+k];
    ws[WB_OFF + k] = W1g[128+k];
  }
  short* BF = (short*)(ws + BF_OFF);
  int w = t >> 9, nt = (t >> 8) & 1, kt = (t >> 6) & 3, lane = t & 63;
  int q = lane >> 4, nlo = lane & 15;
  int n = w*32 + nt*16 + nlo;
  s8v vh;
  #pragma unroll
  for (int jj = 0; jj < 8; ++jj) {
    int k = kt*32 + q*8 + jj;
    vh[jj] = (short)bf16rne(W2g[k*128 + n]);
  }
  *(s8v*)&BF[t*8] = vh;
}

// ---------------- heavy kernel: one (batch, 4-row group), 16 chunks of 16 sites ----------------
// grid 1024 = 64 b * 16 row-groups ; block 256 (4 waves); 4 blocks/CU
// pure bf16-rne MFMA path: 48 MFMA + 6 subplanes per chunk.
// batch partials -> private slot ws[blk*10+n] (no atomics, no zero-init needed)
__global__ __launch_bounds__(256, 4) void k_c1(
    const float* __restrict__ xg, const int* __restrict__ signs,
    const float* __restrict__ b1g, const float* __restrict__ b2g,
    const float* __restrict__ W3g, const float* __restrict__ b3g,
    float* __restrict__ ws)
{
  // AF: [kt(4)][plane(6)] x 512 shorts ; planes: {h, d*wa, d*wb, e*waa, e*wab, e*wbb}
  __shared__ short AF[12288];                 // 24 KB
  __shared__ float xS[6][64];                 // rows i0-1..i0+4  (1.5 KB)
  __shared__ char  zS[6][64];                 // signs as +-1     (384 B)
  __shared__ float EP[16][6][4];              // 1.5 KB

  const int tid  = threadIdx.x;
  const int lane = tid & 63;
  const int w    = tid >> 6;
  const int q    = lane >> 4;
  const int nlo  = lane & 15;

  const int blk = blockIdx.x;
  const int b   = blk >> 4;
  const int i0  = (blk & 15) << 2;            // first of four rows

  // per-thread B-fragment pointer (L2-resident pre-rounded W2)
  const s8v* BhT = (const s8v*)((const short*)(ws + BF_OFF)) + (w*512 + lane);

  float b2j[2], w3j[2];
  #pragma unroll
  for (int nt = 0; nt < 2; ++nt) {
    int j = w*32 + nt*16 + nlo;
    b2j[nt] = b2g[j];
    w3j[nt] = W3g[j];
  }
  float b3v = b3g[0];

  // ---- stage 6 x-rows and 6 sign-rows ----
  for (int t = tid; t < 384; t += 256) {
    int r = t >> 6, j = t & 63;
    int gr = (i0 - 1 + r) & 63;
    xS[r][j] = xg[(size_t)b*NSITE + gr*64 + j];
    int c = ((gr & 1) << 1) | (j & 1);
    zS[r][j] = (char)(2*signs[((c*NB + b)*LL + gr)*LL + j] - 1);
  }
  __syncthreads();

  float racc[10];
  #pragma unroll
  for (int n = 0; n < 10; ++n) racc[n] = 0.f;

  #pragma unroll 1
  for (int ch = 0; ch < 16; ++ch) {
    const int lr = 1 + (ch >> 2);             // local row 1..4
    const int jb = ch & 3;
    const int i  = i0 + (ch >> 2);

    // ---- P1: build A fragments (jj pairs, packed bf16 converts) ----
    {
      int s  = tid & 15;
      int ko = tid >> 4;
      int kt = ko >> 2, kg = ko & 3;
      int j = jb*16 + s, jm = (j+63)&63, jp = (j+1)&63;
      float p = xS[lr][j];
      float l = xS[lr-1][j] + xS[lr+1][j] + xS[lr][jm] + xS[lr][jp] - 4.0f*p;
      short* base = &AF[kt*3072 + (kg*16 + s)*8];
      #pragma unroll
      for (int half = 0; half < 2; ++half) {
        int k0 = ko*8 + half*4;
        float4 wa4 = *(const float4*)(ws + WA_OFF + k0);
        float4 wb4 = *(const float4*)(ws + WB_OFF + k0);
        float4 b14 = *(const float4*)(b1g + k0);
        const float* waA = (const float*)&wa4;
        const float* wbA = (const float*)&wb4;
        const float* b1A = (const float*)&b14;
        u32 v[12];                            // 6 planes x 2 u32 (4 bf16)
        #pragma unroll
        for (int pr = 0; pr < 2; ++pr) {
          float wa0 = waA[pr*2], wa1 = waA[pr*2+1];
          float wb0 = wbA[pr*2], wb1 = wbA[pr*2+1];
          float u0 = p*wa0 + l*wb0 + b1A[pr*2];
          float u1 = p*wa1 + l*wb1 + b1A[pr*2+1];
          float h0, d0, e0, h1, d1, e1;
          gelu3(u0, h0, d0, e0);
          gelu3(u1, h1, d1, e1);
          v[0*2+pr] = pkbf(h0, h1);
          v[1*2+pr] = pkbf(d0*wa0, d1*wa1);
          v[2*2+pr] = pkbf(d0*wb0, d1*wb1);
          float ea0 = e0*wa0, ea1 = e1*wa1;
          float eb0 = e0*wb0, eb1 = e1*wb1;
          v[3*2+pr] = pkbf(ea0*wa0, ea1*wa1);
          v[4*2+pr] = pkbf(ea0*wb0, ea1*wb1);
          v[5*2+pr] = pkbf(eb0*wb0, eb1*wb1);
        }
        short* hb = base + half*4;
        #pragma unroll
        for (int pp = 0; pp < 6; ++pp)
          *(int2*)&hb[pp*512] = make_int2((int)v[pp*2], (int)v[pp*2+1]);
      }
    }
    __syncthreads();

    // ---- P2: MFMA, 6 planes x 2 nt per kt, B prefetched 1-ahead ----
    f4v acc[6][2];
    #pragma unroll
    for (int pp = 0; pp < 6; ++pp)
      #pragma unroll
      for (int nt = 0; nt < 2; ++nt)
        acc[pp][nt] = (f4v){0.f, 0.f, 0.f, 0.f};

    s8v bh0 = BhT[0], bh1 = BhT[256];
    #pragma unroll 1
    for (int kt = 0; kt < 4; ++kt) {
      s8v nh0 = bh0, nh1 = bh1;
      if (kt != 3) {
        int o = (kt + 1) * 64;
        nh0 = BhT[o]; nh1 = BhT[256 + o];
      }
      const short* base = &AF[kt*3072 + lane*8];
      #pragma unroll
      for (int pp = 0; pp < 6; ++pp) {
        s8v ah = *(const s8v*)&base[pp*512];
        acc[pp][0] = __builtin_amdgcn_mfma_f32_16x16x32_bf16(ah, bh0, acc[pp][0], 0, 0, 0);
        acc[pp][1] = __builtin_amdgcn_mfma_f32_16x16x32_bf16(ah, bh1, acc[pp][1], 0, 0, 0);
      }
      bh0 = nh0; bh1 = nh1;
    }

    // ---- P3: epilogue (r-outer; DPP reductions — zero LDS ops) ----
    {
      #pragma unroll
      for (int r = 0; r < 4; ++r) {
        float sh=0.f, sA=0.f, sB=0.f, sa=0.f, sb=0.f, sc=0.f;
        #pragma unroll
        for (int nt = 0; nt < 2; ++nt) {
          float uu = acc[0][nt][r] + b2j[nt];
          float h2, d2, e2;
          gelu3(uu, h2, d2, e2);
          float wd = w3j[nt] * d2, we = w3j[nt] * e2;
          float A  = acc[1][nt][r], Bv = acc[2][nt][r];
          sh += w3j[nt] * h2;
          sA += wd * A;
          sB += wd * Bv;
          sa += we * A * A   + wd * acc[3][nt][r];
          sb += we * A * Bv  + wd * acc[4][nt][r];
          sc += we * Bv * Bv + wd * acc[5][nt][r];
        }
        sh = redjb16(sh); sA = redjb16(sA); sB = redjb16(sB);
        sa = redjb16(sa); sb = redjb16(sb); sc = redjb16(sc);
        if (nlo == 0) {
          int site = q*4 + r;
          EP[site][0][w] = sh;
          EP[site][1][w] = sA;
          EP[site][2][w] = sB;
          EP[site][3][w] = sa;
          EP[site][4][w] = sb;
          EP[site][5][w] = sc;
        }
      }
    }
    __syncthreads();

    // ---- P4: per-site finalize + batch accumulation (16 threads) ----
    if (tid < 16) {
      int s = tid;
      float h = 0.f, RA = 0.f, RB = 0.f, TAa = 0.f, TAb = 0.f, TBb = 0.f;
      #pragma unroll
      for (int ww = 0; ww < 4; ++ww) {
        h   += EP[s][0][ww];
        RA  += EP[s][1][ww];
        RB  += EP[s][2][ww];
        TAa += EP[s][3][ww];
        TAb += EP[s][4][ww];
        TBb += EP[s][5][ww];
      }
      h += b3v;
      float* P = ws + PL_OFF;
      int j = jb*16 + s;
      size_t site = (size_t)b*NSITE + i*64 + j;
      P[0*BN + site] = h;
      P[1*BN + site] = RA;
      P[2*BN + site] = RB;
      P[3*BN + site] = TAa;
      P[4*BN + site] = TAb;
      P[5*BN + site] = TBb;

      int jm = (j+63)&63, jp = (j+1)&63;
      int c0 = ((i & 1) << 1) | (j & 1);
      float hd[4] = {0.f, 0.f, 0.f, 0.f};
      hd[c0]     = (float)zS[lr][j] * (RA - 4.0f*RB);
      hd[c0 ^ 1] = (float)(zS[lr][jm] + zS[lr][jp]) * RB;
      hd[c0 ^ 2] = (float)(zS[lr-1][j] + zS[lr+1][j]) * RB;
      racc[0] += h;
      racc[1] += h*h;
      #pragma unroll
      for (int cc = 0; cc < 4; ++cc) {
        racc[2+cc] += hd[cc];
        racc[6+cc] += h*hd[cc];
      }
    }
  }

  // ---- final batch reduction: write this block's partials to its private slot ----
  if (tid < 16) {
    #pragma unroll
    for (int n = 0; n < 10; ++n) racc[n] = redjb16(racc[n]);
    if (tid == 0) {
      #pragma unroll
      for (int n = 0; n < 10; ++n) ws[RED_OFF + blk*10 + n] = racc[n];
    }
  }
}

// ---------------- stencil + fused head calculus (slot-summed, no atomics) ----------------
__global__ __launch_bounds__(256, 1) void k_c2(
    const int* __restrict__ signs,
    const float* __restrict__ aW1g, const float* __restrict__ ab1g,
    const float* __restrict__ aW2g,
    float* __restrict__ ws, float* __restrict__ out)
{
  __shared__ float part[4];
  __shared__ float coefL[10];
  __shared__ float redS[10];
  __shared__ float cbS[6][64];
  int blk = blockIdx.x;
  int b = blk >> 4, rg = blk & 15;
  int tid = threadIdx.x;

  // sum the 16 per-block partials for this batch (deterministic)
  if (tid < 10) {
    float s = 0.f;
    const float* rp = ws + RED_OFF + (b*16)*10 + tid;
    #pragma unroll
    for (int g = 0; g < 16; ++g) s += rp[g*10];
    redS[tid] = s;
  }
  __syncthreads();

  if (tid < 64) {
    int k = tid;
    const float Nf = 4096.0f, Nm1 = 4095.0f;
    float S1 = redS[0], S2 = redS[1];
    float m = S1/Nf, q = S2/Nf;
    float v = (S2 - S1*S1/Nf)/Nm1;
    float w0 = aW1g[k], w1 = aW1g[64+k], w2 = aW1g[128+k];
    float t = m*w0 + v*w1 + q*w2 + ab1g[k];
    float gh, gd, ge;
    gelu3(t, gh, gd, ge);
    float o = aW2g[k];
    float g1o = gd*o, g2o = ge*o;
    float da0 = w0*g1o, da1 = w1*g1o, da2 = w2*g1o;
    float M00 = w0*w0*g2o, M01 = w0*w1*g2o, M02 = w0*w2*g2o;
    float M11 = w1*w1*g2o, M12 = w1*w2*g2o, M22 = w2*w2*g2o;
    da0 = red64(da0); da1 = red64(da1); da2 = red64(da2);
    M00 = red64(M00); M01 = red64(M01); M02 = red64(M02);
    M11 = red64(M11); M12 = red64(M12); M22 = red64(M22);
    if (k == 0) {
      coefL[0] = da0/Nf - 2.0f*da1*m/Nm1;
      coefL[1] = 2.0f*da1/Nm1 + 2.0f*da2/Nf;
      #pragma unroll
      for (int c = 0; c < 4; ++c) {
        float s1 = redS[2 + c], s2 = redS[6 + c];
        float md = s1/Nf, qd = 2.0f*s2/Nf;
        float vd = (2.0f*s2 - 2.0f*S1*s1/Nf)/Nm1;
        float dd0 = M00*md + M01*vd + M02*qd;
        float dd1 = M01*md + M11*vd + M12*qd;
        float dd2 = M02*md + M12*vd + M22*qd;
        coefL[2+c] = dd0/Nf - 2.0f*(dd1*m + da1*md)/Nm1;
        coefL[6+c] = 2.0f*dd1/Nm1 + 2.0f*dd2/Nf;
      }
    }
  }
  __syncthreads();

  const float* P = ws + PL_OFF;
  int base = b*NSITE;
  float alpha = coefL[0], beta = coefL[1];

  // stage cb = (alpha + beta*h) * RB for rows rg*4-1 .. rg*4+4
  for (int t = tid; t < 384; t += 256) {
    int r = t >> 6, jj = t & 63;
    int gr = (rg*4 - 1 + r) & 63;
    int sidx = base + gr*64 + jj;
    cbS[r][jj] = (alpha + beta*P[sidx]) * P[2*BN + sidx];
  }
  __syncthreads();

  int rl = tid >> 6, j = tid & 63;
  int i = rg*4 + rl;
  int im=(i+63)&63, ip=(i+1)&63, jm=(j+63)&63, jp=(j+1)&63;
  int s  = base + i*64 + j;
  float h  = P[s], RA = P[BN+s], RB = P[2*BN+s];
  float TAa= P[3*BN+s], TAb = P[4*BN+s], TBb = P[5*BN+s];
  float g  = alpha + beta*h;
  int lr2 = rl + 1;
  float cb  = cbS[lr2][j];
  float cbu = cbS[lr2-1][j], cbd = cbS[lr2+1][j];
  float cbl = cbS[lr2][jm],  cbr = cbS[lr2][jp];
  float grad = g*RA + (cbu + cbd + cbl + cbr - 4.0f*cb);
  out[(size_t)b*4097 + i*64 + j] = grad;

  int c0 = ((i & 1) << 1) | (j & 1);
  int c1 = c0 ^ 1, c2 = c0 ^ 2;
  float zv = 2.0f*(float)signs[((c0*NB + b)*LL + i )*LL + j ] - 1.0f;
  float zl = 2.0f*(float)signs[((c1*NB + b)*LL + i )*LL + jm] - 1.0f;
  float zr = 2.0f*(float)signs[((c1*NB + b)*LL + i )*LL + jp] - 1.0f;
  float zu = 2.0f*(float)signs[((c2*NB + b)*LL + im)*LL + j ] - 1.0f;
  float zd = 2.0f*(float)signs[((c2*NB + b)*LL + ip)*LL + j ] - 1.0f;
  float sjr = zl + zr, sud = zu + zd;
  float hd0 = zv*(RA - 4.0f*RB);
  float hd1 = sjr*RB, hd2 = sud*RB;
  float gd0 = coefL[2+c0] + coefL[6+c0]*h + beta*hd0;
  float gd1 = coefL[2+c1] + coefL[6+c1]*h + beta*hd1;
  float gd2 = coefL[2+c2] + coefL[6+c2]*h + beta*hd2;
  float ca0 = gd0*RA + g*( zv*TAa - 4.0f*zv*TAb );
  float cb0 = gd0*RB + g*( zv*TAb - 4.0f*zv*TBb );
  float cb1 = gd1*RB + g*( sjr*TBb );
  float cb2 = gd2*RB + g*( sud*TBb );
  float contrib = zv*ca0 - 4.0f*zv*cb0 + sjr*cb1 + sud*cb2;

  float vsum = red64(contrib);
  int wv = tid >> 6;
  if ((tid & 63) == 0) part[wv] = vsum;
  __syncthreads();
  if (tid == 0)
    ws[LP_OFF + blk] = part[0] + part[1] + part[2] + part[3];
}

// ---------------- tiny tail: sum 16 lapl partials per batch ----------------
__global__ void k_e(const float* __restrict__ ws, float* __restrict__ out){
  int b = threadIdx.x;
  if (b < 64) {
    float s = 0.f;
    #pragma unroll
    for (int g = 0; g < 16; ++g) s += ws[LP_OFF + b*16 + g];
    out[(size_t)b*4097 + 4096] = s;
  }
}

extern "C" void kernel_launch(void* const* d_in, const int* in_sizes, int n_in,
                              void* d_out, int out_size, void* d_ws, size_t ws_size,
                              hipStream_t stream) {
  const float* xg    = (const float*)d_in[0];
  const int*   signs = (const int*)d_in[1];
  const float* W1    = (const float*)d_in[2];
  const float* b1    = (const float*)d_in[3];
  const float* W2    = (const float*)d_in[4];
  const float* b2    = (const float*)d_in[5];
  const float* W3    = (const float*)d_in[6];
  const float* b3    = (const float*)d_in[7];
  const float* aW1   = (const float*)d_in[8];
  const float* ab1   = (const float*)d_in[9];
  const float* aW2   = (const float*)d_in[10];
  float* ws  = (float*)d_ws;
  float* out = (float*)d_out;

  hipLaunchKernelGGL(k_pre, dim3(8),    dim3(256), 0, stream, W1, W2, ws);
  hipLaunchKernelGGL(k_c1,  dim3(1024), dim3(256), 0, stream,
                     xg, signs, b1, b2, W3, b3, ws);
  hipLaunchKernelGGL(k_c2,  dim3(1024), dim3(256), 0, stream,
                     signs, aW1, ab1, aW2, ws, out);
  hipLaunchKernelGGL(k_e,   dim3(1),    dim3(64),  0, stream, ws, out);
}